// Round 4
// baseline (545.857 us; speedup 1.0000x reference)
//
#include <hip/hip_runtime.h>
#include <hip/hip_bf16.h>
#include <stdint.h>

#define SEQ     4096
#define NBATCH  16
#define DMODEL  768
#define NHEAD   12
#define HDIM    64
#define WINSZ   64
#define SHIFT_T 32
#define QKV_N   (3*DMODEL)   // 2304

typedef __attribute__((ext_vector_type(8)))  short bf16x8;
typedef __attribute__((ext_vector_type(4)))  float f32x4;
typedef __attribute__((ext_vector_type(16))) float f32x16;

static __device__ __forceinline__ unsigned short f2bf(float f) {
  union { float f; unsigned u; } v; v.f = f;
  unsigned r = v.u + 0x7fffu + ((v.u >> 16) & 1u);
  return (unsigned short)(r >> 16);
}

#define G2L(gp, lp) __builtin_amdgcn_global_load_lds( \
    (const __attribute__((address_space(1))) unsigned*)(const void*)(gp), \
    (__attribute__((address_space(3))) unsigned*)(void*)(lp), 16, 0, 0)

// ---- cast x (fp32) -> bf16 with +SHIFT roll fused
__global__ void k_cvt_x(const float* __restrict__ x, unsigned short* __restrict__ xb,
                        long long c0, long long n8) {
  for (long long i = (long long)blockIdx.x*blockDim.x + threadIdx.x; i < n8;
       i += (long long)gridDim.x*blockDim.x) {
    long long e = i*8;
    int d = (int)(e % DMODEL);
    long long gt = c0 + e / DMODEL;
    int t = (int)(gt & (SEQ-1));
    long long b = gt >> 12;
    int ts = (t - SHIFT_T) & (SEQ-1);
    const float* src = x + (((b << 12) + ts) * (long long)DMODEL + d);
    float4 a0 = *(const float4*)src;
    float4 a1 = *(const float4*)(src + 4);
    bf16x8 o;
    o[0]=(short)f2bf(a0.x); o[1]=(short)f2bf(a0.y); o[2]=(short)f2bf(a0.z); o[3]=(short)f2bf(a0.w);
    o[4]=(short)f2bf(a1.x); o[5]=(short)f2bf(a1.y); o[6]=(short)f2bf(a1.z); o[7]=(short)f2bf(a1.w);
    *(bf16x8*)(xb + e) = o;
  }
}

__global__ void k_cvt_w(const float* __restrict__ w, unsigned short* __restrict__ wb, int n8) {
  int i = blockIdx.x*blockDim.x + threadIdx.x;
  if (i >= n8) return;
  float4 a0 = ((const float4*)w)[2*i];
  float4 a1 = ((const float4*)w)[2*i+1];
  bf16x8 o;
  o[0]=(short)f2bf(a0.x); o[1]=(short)f2bf(a0.y); o[2]=(short)f2bf(a0.z); o[3]=(short)f2bf(a0.w);
  o[4]=(short)f2bf(a1.x); o[5]=(short)f2bf(a1.y); o[6]=(short)f2bf(a1.z); o[7]=(short)f2bf(a1.w);
  ((bf16x8*)wb)[i] = o;
}

// ---- 256x256 bf16 GEMM, 32x32x16 MFMA, one barrier-pair per K32-slice,
// 4-slot LDS ring, counted vmcnt(4), T2 swizzle (linear dest / pre-swizzled
// source / XOR'd reads). C[m,n] = sum_k A[m,k]*B[n,k] + bias[n].
#define MFMA32(a,b,c) __builtin_amdgcn_mfma_f32_32x32x16_bf16(a,b,c,0,0,0)

template<int MODE>
__global__ __launch_bounds__(512, 1)
void k_gemm256(const unsigned short* __restrict__ A, const unsigned short* __restrict__ Bw,
               const float* __restrict__ bias, unsigned short* __restrict__ Cb,
               float* __restrict__ Cf, int M, int N, int K, int nTN, long long c0) {
  __shared__ char lds[4*32768];               // 4-slot ring, 32 KB/slice (A16K+B16K)
  const int nsl = K >> 5;                     // K-slices of 32 (768 -> 24, %4==0)
  int nwg = gridDim.x;
  int cpx = nwg >> 3;
  int wg  = (blockIdx.x & 7) * cpx + (blockIdx.x >> 3);   // XCD-contiguous
  int bm = wg / nTN, bn = wg - bm*nTN;
  long long m0 = (long long)bm * 256;
  int n0 = bn * 256;
  int tid = threadIdx.x;
  int lane = tid & 63, wid = tid >> 6;
  int wr = wid >> 2, wc = wid & 3;            // 2M x 4N waves, each 128x64 of C
  int l31 = lane & 31, h = lane >> 5;

  // staging: thread fills LINEAR LDS [tid*16, +16) per 8KB region; global src
  // is the inverse-swizzled logical spot (involution P ^= ((P>>7)&7)<<4).
  const long long K2 = 2LL * K;
  int L  = tid * 16;
  int Ls = L ^ (((L >> 7) & 7) << 4);
  int srow = Ls >> 6, scol = Ls & 63;
  const char* gA0 = (const char*)A + (m0 + srow) * K2 + scol;
  const char* gA1 = (const char*)A + (m0 + 128 + srow) * K2 + scol;
  const char* gB0 = (const char*)Bw + (long long)(n0 + srow) * K2 + scol;
  const char* gB1 = (const char*)Bw + (long long)(n0 + 128 + srow) * K2 + scol;

  // frag-read bases (region-local, swizzled). ks=1 base = base^32 (bit5 pure).
  int axor  = ((l31 >> 1) & 7) << 4;
  int aoff0 = wr*8192 + ((l31*64 + h*16) ^ axor);
  int aoff1 = aoff0 ^ 32;
  int boff0 = 16384 + (wc >> 1)*8192 + ((((wc & 1)*64 + l31)*64 + h*16) ^ axor);
  int boff1 = boff0 ^ 32;

  f32x16 acc[4][2];
  #pragma unroll
  for (int i = 0; i < 4; ++i)
    #pragma unroll
    for (int j = 0; j < 2; ++j)
      #pragma unroll
      for (int e = 0; e < 16; ++e) acc[i][j][e] = 0.f;

  // ---- prologue: stage slices 0 (slot0) and 1 (slot1), drain slice 0
  G2L(gA0,      lds + L);
  G2L(gA1,      lds + 8192  + L);
  G2L(gB0,      lds + 16384 + L);
  G2L(gB1,      lds + 24576 + L);
  G2L(gA0 + 64, lds + 32768 + L);
  G2L(gA1 + 64, lds + 32768 + 8192  + L);
  G2L(gB0 + 64, lds + 32768 + 16384 + L);
  G2L(gB1 + 64, lds + 32768 + 24576 + L);
  gA0 += 128; gA1 += 128; gB0 += 128; gB1 += 128;   // now point at slice 2
  asm volatile("s_waitcnt vmcnt(4)" ::: "memory");
  __builtin_amdgcn_sched_barrier(0);
  __builtin_amdgcn_s_barrier();

  // one K32-slice: 12 ds_read + stage(s+2) + vmcnt + barrier + 16 MFMA + barrier
#define SLICE(SLOT, STSLOT, DO_STAGE, VMASM) do {                          \
    const char* sb = lds + (SLOT)*32768;                                   \
    bf16x8 a0 = *(const bf16x8*)(sb + aoff0);                              \
    bf16x8 a1 = *(const bf16x8*)(sb + aoff0 + 2048);                       \
    bf16x8 a2 = *(const bf16x8*)(sb + aoff0 + 4096);                       \
    bf16x8 a3 = *(const bf16x8*)(sb + aoff0 + 6144);                       \
    bf16x8 a4 = *(const bf16x8*)(sb + aoff1);                              \
    bf16x8 a5 = *(const bf16x8*)(sb + aoff1 + 2048);                       \
    bf16x8 a6 = *(const bf16x8*)(sb + aoff1 + 4096);                       \
    bf16x8 a7 = *(const bf16x8*)(sb + aoff1 + 6144);                       \
    bf16x8 b0 = *(const bf16x8*)(sb + boff0);                              \
    bf16x8 b1 = *(const bf16x8*)(sb + boff0 + 2048);                       \
    bf16x8 b2 = *(const bf16x8*)(sb + boff1);                              \
    bf16x8 b3 = *(const bf16x8*)(sb + boff1 + 2048);                       \
    if (DO_STAGE) {                                                        \
      char* st = lds + (STSLOT)*32768;                                     \
      G2L(gA0, st + L);                                                    \
      G2L(gA1, st + 8192  + L);                                            \
      G2L(gB0, st + 16384 + L);                                            \
      G2L(gB1, st + 24576 + L);                                            \
    }                                                                      \
    gA0 += 64; gA1 += 64; gB0 += 64; gB1 += 64;                            \
    asm volatile(VMASM ::: "memory");                                      \
    __builtin_amdgcn_sched_barrier(0);                                     \
    __builtin_amdgcn_s_barrier();                                          \
    __builtin_amdgcn_s_setprio(1);                                         \
    acc[0][0]=MFMA32(a0,b0,acc[0][0]); acc[0][1]=MFMA32(a0,b1,acc[0][1]);  \
    acc[1][0]=MFMA32(a1,b0,acc[1][0]); acc[1][1]=MFMA32(a1,b1,acc[1][1]);  \
    acc[2][0]=MFMA32(a2,b0,acc[2][0]); acc[2][1]=MFMA32(a2,b1,acc[2][1]);  \
    acc[3][0]=MFMA32(a3,b0,acc[3][0]); acc[3][1]=MFMA32(a3,b1,acc[3][1]);  \
    acc[0][0]=MFMA32(a4,b2,acc[0][0]); acc[0][1]=MFMA32(a4,b3,acc[0][1]);  \
    acc[1][0]=MFMA32(a5,b2,acc[1][0]); acc[1][1]=MFMA32(a5,b3,acc[1][1]);  \
    acc[2][0]=MFMA32(a6,b2,acc[2][0]); acc[2][1]=MFMA32(a6,b3,acc[2][1]);  \
    acc[3][0]=MFMA32(a7,b2,acc[3][0]); acc[3][1]=MFMA32(a7,b3,acc[3][1]);  \
    __builtin_amdgcn_s_setprio(0);                                         \
    __builtin_amdgcn_sched_barrier(0);                                     \
    __builtin_amdgcn_s_barrier();                                          \
  } while (0)

  for (int os = 0; os + 8 <= nsl; os += 4) {
    SLICE(0, 2, true, "s_waitcnt vmcnt(4)");
    SLICE(1, 3, true, "s_waitcnt vmcnt(4)");
    SLICE(2, 0, true, "s_waitcnt vmcnt(4)");
    SLICE(3, 1, true, "s_waitcnt vmcnt(4)");
  }
  // tail 4 slices: stage s+2 only for first two, then drain
  SLICE(0, 2, true,  "s_waitcnt vmcnt(4)");
  SLICE(1, 3, true,  "s_waitcnt vmcnt(4)");
  SLICE(2, 0, false, "s_waitcnt vmcnt(0)");
  SLICE(3, 1, false, "");
#undef SLICE

  // ---- epilogue: C/D 32x32 layout: col=lane&31, row=(reg&3)+8*(reg>>2)+4*h
  #pragma unroll
  for (int mt = 0; mt < 4; ++mt) {
    #pragma unroll
    for (int nt = 0; nt < 2; ++nt) {
      int n = n0 + wc*64 + nt*32 + l31;
      float bv = bias[n];
      #pragma unroll
      for (int reg = 0; reg < 16; ++reg) {
        int rin = (reg & 3) + 8*(reg >> 2) + 4*h;
        long long m = m0 + wr*128 + mt*32 + rin;
        float v = acc[mt][nt][reg] + bv;
        if (MODE == 0) {
          Cb[m * (long long)N + n] = f2bf(v);
        } else {
          long long gm = c0 + m;
          long long om = (gm & ~(long long)(SEQ-1)) | ((gm - SHIFT_T) & (long long)(SEQ-1));
          Cf[om * (long long)N + n] = v;
        }
      }
    }
  }
}

// ---- per-(window,head) attention: S = QK^T*scale + rel_bias, softmax, O = P V
__global__ __launch_bounds__(256, 4)
void k_attn(const unsigned short* __restrict__ qkv, const float* __restrict__ rel_bias,
            unsigned short* __restrict__ y) {
  int w = blockIdx.x / NHEAD;
  int h = blockIdx.x - w*NHEAD;
  __shared__ unsigned short sQ[64*72], sK[64*72], sV[64*72];
  __shared__ unsigned short sP[4][16*72];
  __shared__ float rb[128];
  int tid = threadIdx.x, lane = tid & 63, wid = tid >> 6;
  int cl = lane & 15, g4 = lane >> 4;

  if (tid < 2*WINSZ - 1) rb[tid] = rel_bias[h*(2*WINSZ-1) + tid];

  const unsigned short* base = qkv + (long long)w*WINSZ*QKV_N + h*HDIM;
  #pragma unroll
  for (int pass = 0; pass < 2; ++pass) {
    int row = (tid >> 3) + pass*32;
    int ch  = tid & 7;
    const unsigned short* src = base + (long long)row*QKV_N + ch*8;
    *(bf16x8*)(sQ + row*72 + ch*8) = *(const bf16x8*)(src);
    *(bf16x8*)(sK + row*72 + ch*8) = *(const bf16x8*)(src + DMODEL);
    *(bf16x8*)(sV + row*72 + ch*8) = *(const bf16x8*)(src + 2*DMODEL);
  }
  __syncthreads();

  f32x4 sc[4];
  #pragma unroll
  for (int nt = 0; nt < 4; ++nt) sc[nt] = (f32x4){0.f,0.f,0.f,0.f};
  #pragma unroll
  for (int kk = 0; kk < 2; ++kk) {
    bf16x8 aq = *(const bf16x8*)(sQ + (wid*16 + cl)*72 + kk*32 + g4*8);
    #pragma unroll
    for (int nt = 0; nt < 4; ++nt) {
      bf16x8 bk = *(const bf16x8*)(sK + (nt*16 + cl)*72 + kk*32 + g4*8);
      sc[nt] = __builtin_amdgcn_mfma_f32_16x16x32_bf16(aq, bk, sc[nt], 0, 0, 0);
    }
  }

  float pv[4][4];
  #pragma unroll
  for (int r = 0; r < 4; ++r) {
    int qi = wid*16 + g4*4 + r;
    float mx = -1e30f;
    #pragma unroll
    for (int nt = 0; nt < 4; ++nt) {
      int kj = nt*16 + cl;
      float v = sc[nt][r]*0.125f + rb[kj - qi + (WINSZ-1)];
      pv[nt][r] = v;
      mx = fmaxf(mx, v);
    }
    #pragma unroll
    for (int m = 1; m < 16; m <<= 1) mx = fmaxf(mx, __shfl_xor(mx, m, 64));
    float sum = 0.f;
    #pragma unroll
    for (int nt = 0; nt < 4; ++nt) { float e = __expf(pv[nt][r]-mx); pv[nt][r] = e; sum += e; }
    #pragma unroll
    for (int m = 1; m < 16; m <<= 1) sum += __shfl_xor(sum, m, 64);
    float inv = 1.f / sum;
    #pragma unroll
    for (int nt = 0; nt < 4; ++nt)
      sP[wid][(g4*4+r)*72 + nt*16 + cl] = f2bf(pv[nt][r]*inv);
  }

  f32x4 o[4];
  #pragma unroll
  for (int nt = 0; nt < 4; ++nt) o[nt] = (f32x4){0.f,0.f,0.f,0.f};
  #pragma unroll
  for (int kk = 0; kk < 2; ++kk) {
    bf16x8 ap = *(const bf16x8*)(&sP[wid][cl*72 + kk*32 + g4*8]);
    #pragma unroll
    for (int nt = 0; nt < 4; ++nt) {
      bf16x8 bv;
      #pragma unroll
      for (int j = 0; j < 8; ++j)
        bv[j] = (short)sV[(kk*32 + g4*8 + j)*72 + nt*16 + cl];
      o[nt] = __builtin_amdgcn_mfma_f32_16x16x32_bf16(ap, bv, o[nt], 0, 0, 0);
    }
  }

  long long tokbase = (long long)w * WINSZ;
  #pragma unroll
  for (int nt = 0; nt < 4; ++nt)
    #pragma unroll
    for (int r = 0; r < 4; ++r) {
      int row = wid*16 + g4*4 + r;
      y[(tokbase + row) * (long long)DMODEL + h*HDIM + nt*16 + cl] = f2bf(o[nt][r]);
    }
}

extern "C" void kernel_launch(void* const* d_in, const int* in_sizes, int n_in,
                              void* d_out, int out_size, void* d_ws, size_t ws_size,
                              hipStream_t stream) {
  const float* x      = (const float*)d_in[0];
  const float* qkv_w  = (const float*)d_in[1];
  const float* qkv_b  = (const float*)d_in[2];
  const float* proj_w = (const float*)d_in[3];
  const float* proj_b = (const float*)d_in[4];
  const float* rel_b  = (const float*)d_in[5];
  float* out = (float*)d_out;

  const long long NTOK = (long long)NBATCH * SEQ;    // 65536
  const size_t wbytes = (size_t)QKV_N*DMODEL*2 + (size_t)DMODEL*DMODEL*2;

  int C = 16;
  for (int c : {1, 2, 4, 8, 16}) {
    size_t tpc = (size_t)NTOK / c;
    size_t need = tpc*QKV_N*2 + tpc*DMODEL*2 + wbytes;
    if (need <= ws_size) { C = c; break; }
  }
  long long tpc = NTOK / C;

  char* ws = (char*)d_ws;
  unsigned short* qkvb = (unsigned short*)ws;
  unsigned short* xb   = (unsigned short*)(ws + (size_t)tpc*QKV_N*2);
  unsigned short* wq   = (unsigned short*)(ws + (size_t)tpc*QKV_N*2 + (size_t)tpc*DMODEL*2);
  unsigned short* wp   = wq + (size_t)QKV_N*DMODEL;

  k_cvt_w<<<(QKV_N*DMODEL/8 + 255)/256, 256, 0, stream>>>(qkv_w, wq, QKV_N*DMODEL/8);
  k_cvt_w<<<(DMODEL*DMODEL/8 + 255)/256, 256, 0, stream>>>(proj_w, wp, DMODEL*DMODEL/8);

  for (int c = 0; c < C; ++c) {
    long long c0 = (long long)c * tpc;
    long long n8 = tpc * DMODEL / 8;
    int cvtGrid = (int)((n8 + 255) / 256); if (cvtGrid > 2048) cvtGrid = 2048;
    k_cvt_x<<<cvtGrid, 256, 0, stream>>>(x, xb, c0, n8);

    int mT = (int)(tpc / 256);
    k_gemm256<0><<<mT * (QKV_N/256), 512, 0, stream>>>(xb, wq, qkv_b, qkvb, nullptr,
                                                       (int)tpc, QKV_N, DMODEL, QKV_N/256, c0);
    k_attn<<<(int)(tpc/WINSZ) * NHEAD, 256, 0, stream>>>(qkvb, rel_b, xb /*reuse as y*/);
    k_gemm256<1><<<mT * (DMODEL/256), 512, 0, stream>>>(xb, wp, proj_b, nullptr, out,
                                                        (int)tpc, DMODEL, DMODEL, DMODEL/256, c0);
  }
}

// Round 5
// 503.272 us; speedup vs baseline: 1.0846x; 1.0846x over previous
//
#include <hip/hip_runtime.h>
#include <hip/hip_bf16.h>
#include <stdint.h>

#define SEQ     4096
#define NBATCH  16
#define DMODEL  768
#define NHEAD   12
#define HDIM    64
#define WINSZ   64
#define SHIFT_T 32
#define QKV_N   (3*DMODEL)   // 2304

typedef __attribute__((ext_vector_type(8)))  short bf16x8;
typedef __attribute__((ext_vector_type(4)))  float f32x4;

static __device__ __forceinline__ unsigned short f2bf(float f) {
  union { float f; unsigned u; } v; v.f = f;
  unsigned r = v.u + 0x7fffu + ((v.u >> 16) & 1u);
  return (unsigned short)(r >> 16);
}

#define G2L(gp, lp) __builtin_amdgcn_global_load_lds( \
    (const __attribute__((address_space(1))) unsigned*)(const void*)(gp), \
    (__attribute__((address_space(3))) unsigned*)(void*)(lp), 16, 0, 0)

// ---- cast x (fp32) -> bf16 with +SHIFT roll fused
__global__ void k_cvt_x(const float* __restrict__ x, unsigned short* __restrict__ xb,
                        long long c0, long long n8) {
  for (long long i = (long long)blockIdx.x*blockDim.x + threadIdx.x; i < n8;
       i += (long long)gridDim.x*blockDim.x) {
    long long e = i*8;
    int d = (int)(e % DMODEL);
    long long gt = c0 + e / DMODEL;
    int t = (int)(gt & (SEQ-1));
    long long b = gt >> 12;
    int ts = (t - SHIFT_T) & (SEQ-1);
    const float* src = x + (((b << 12) + ts) * (long long)DMODEL + d);
    float4 a0 = *(const float4*)src;
    float4 a1 = *(const float4*)(src + 4);
    bf16x8 o;
    o[0]=(short)f2bf(a0.x); o[1]=(short)f2bf(a0.y); o[2]=(short)f2bf(a0.z); o[3]=(short)f2bf(a0.w);
    o[4]=(short)f2bf(a1.x); o[5]=(short)f2bf(a1.y); o[6]=(short)f2bf(a1.z); o[7]=(short)f2bf(a1.w);
    *(bf16x8*)(xb + e) = o;
  }
}

__global__ void k_cvt_w(const float* __restrict__ w, unsigned short* __restrict__ wb, int n8) {
  int i = blockIdx.x*blockDim.x + threadIdx.x;
  if (i >= n8) return;
  float4 a0 = ((const float4*)w)[2*i];
  float4 a1 = ((const float4*)w)[2*i+1];
  bf16x8 o;
  o[0]=(short)f2bf(a0.x); o[1]=(short)f2bf(a0.y); o[2]=(short)f2bf(a0.z); o[3]=(short)f2bf(a0.w);
  o[4]=(short)f2bf(a1.x); o[5]=(short)f2bf(a1.y); o[6]=(short)f2bf(a1.z); o[7]=(short)f2bf(a1.w);
  ((bf16x8*)wb)[i] = o;
}

// ---- 256x256 bf16 GEMM, faithful m201-style 4-phase/K64-tile schedule.
// C[m,n] = sum_k A[m,k]*B[n,k] + bias[n].
// LDS: 2 x 64KB dbuf; per buf: A 256x64 (4x8KB regions of 64 rows), B same.
// Rows 128 B; swizzle involution per region: P ^= ((P>>7)&7)<<4.
// Staging: 8 G2L/tile (FIFO order B0,B1,B2,B3,A0,A2,A1,A3), 2 per phase,
// issued one tile ahead. Counted waits: vmcnt(2) at ph4-end gates next tile's
// ph1/ph2 reads (via trailing barrier); vmcnt(4) at ph2-end gates ph3/ph4.
// B-fragments register-cached across the tile (8 reads/tile/wave).
#define MFMA16(a,b,c) __builtin_amdgcn_mfma_f32_16x16x32_bf16(a,b,c,0,0,0)
#define LDS8(p) (*(const bf16x8*)(p))

template<int MODE>
__global__ __launch_bounds__(512, 1)
void k_gemm256(const unsigned short* __restrict__ A, const unsigned short* __restrict__ Bw,
               const float* __restrict__ bias, unsigned short* __restrict__ Cb,
               float* __restrict__ Cf, int M, int N, int K, int nTN, long long c0) {
  __shared__ char lds[131072];
  const int nt = K >> 6;                      // K64 tiles (768 -> 12, even)
  int nwg = gridDim.x;
  int cpx = nwg >> 3;
  int wg  = (blockIdx.x & 7) * cpx + (blockIdx.x >> 3);   // XCD-contiguous
  int bm = wg / nTN, bn = wg - bm*nTN;
  long long m0 = (long long)bm * 256;
  int n0 = bn * 256;
  int tid = threadIdx.x;
  int lane = tid & 63, wid = tid >> 6;
  int wr = wid >> 2, wc = wid & 3;            // 2M x 4N waves, each 128x64 of C
  int cl = lane & 15, g4 = lane >> 4;

  // staging sources: linear LDS dest L, inverse-swizzled global source
  const long long K2 = 2LL * K;
  int L  = tid * 16;
  int Ls = L ^ (((L >> 7) & 7) << 4);
  int srow = Ls >> 7, scol = Ls & 127;        // row 0..63 within region, byte col
  const char* gAr0 = (const char*)A + (m0 +       srow) * K2 + scol;
  const char* gAr1 = (const char*)A + (m0 +  64 + srow) * K2 + scol;
  const char* gAr2 = (const char*)A + (m0 + 128 + srow) * K2 + scol;
  const char* gAr3 = (const char*)A + (m0 + 192 + srow) * K2 + scol;
  const char* gBr0 = (const char*)Bw + (long long)(n0 +       srow) * K2 + scol;
  const char* gBr1 = (const char*)Bw + (long long)(n0 +  64 + srow) * K2 + scol;
  const char* gBr2 = (const char*)Bw + (long long)(n0 + 128 + srow) * K2 + scol;
  const char* gBr3 = (const char*)Bw + (long long)(n0 + 192 + srow) * K2 + scol;

  // frag-read lane offsets: row cl at 128 B pitch, kk half via ^64
  int p0 = cl*128 + ((g4*16) ^ ((cl & 7) << 4));
  int p1 = p0 ^ 64;
  int RA0 = wr*16384;            // A region for phases 1-2 (rows 0-63 of half)
  int RA1 = wr*16384 + 8192;     // phases 3-4
  int BB  = 32768 + wc*8192;     // B region of this wave's 64 cols

  f32x4 acc[8][4];
  #pragma unroll
  for (int i = 0; i < 8; ++i)
    #pragma unroll
    for (int j = 0; j < 4; ++j) acc[i][j] = (f32x4){0.f,0.f,0.f,0.f};

#define MMPH(MA, MB, x0, x1, y0, y1) \
  acc[MA][0]=MFMA16(x0,b00,acc[MA][0]); acc[MA][1]=MFMA16(x0,b10,acc[MA][1]); \
  acc[MA][2]=MFMA16(x0,b20,acc[MA][2]); acc[MA][3]=MFMA16(x0,b30,acc[MA][3]); \
  acc[MB][0]=MFMA16(y0,b00,acc[MB][0]); acc[MB][1]=MFMA16(y0,b10,acc[MB][1]); \
  acc[MB][2]=MFMA16(y0,b20,acc[MB][2]); acc[MB][3]=MFMA16(y0,b30,acc[MB][3]); \
  acc[MA][0]=MFMA16(x1,b01,acc[MA][0]); acc[MA][1]=MFMA16(x1,b11,acc[MA][1]); \
  acc[MA][2]=MFMA16(x1,b21,acc[MA][2]); acc[MA][3]=MFMA16(x1,b31,acc[MA][3]); \
  acc[MB][0]=MFMA16(y1,b01,acc[MB][0]); acc[MB][1]=MFMA16(y1,b11,acc[MB][1]); \
  acc[MB][2]=MFMA16(y1,b21,acc[MB][2]); acc[MB][3]=MFMA16(y1,b31,acc[MB][3]);

#define BARR __builtin_amdgcn_s_barrier()
#define SBAR __builtin_amdgcn_sched_barrier(0)
#define LGK0 do { asm volatile("s_waitcnt lgkmcnt(0)" ::: "memory"); SBAR; } while(0)

  // TILE: read buf RD, stage next tile into ST (if DOSTAGE).
  // WB = wait string at ph2-end ("s_waitcnt vmcnt(4)" steady / "vmcnt(0)" tail)
  // DOWA: emit vmcnt(2) at ph4-end (skip on last tile)
#define TILE(RD, ST, DOSTAGE, WBSTR, DOWA) do {                               \
    const char* rb = (RD); char* stb = (ST);                                  \
    bf16x8 b00,b01,b10,b11,b20,b21,b30,b31;                                   \
    { /* phase 1: A mf0,1 + all B; stage B0,B1 */                             \
      bf16x8 x0 = LDS8(rb + RA0        + p0), x1 = LDS8(rb + RA0        + p1);\
      bf16x8 y0 = LDS8(rb + RA0 + 2048 + p0), y1 = LDS8(rb + RA0 + 2048 + p1);\
      b00 = LDS8(rb + BB        + p0);  b01 = LDS8(rb + BB        + p1);      \
      b10 = LDS8(rb + BB + 2048 + p0);  b11 = LDS8(rb + BB + 2048 + p1);      \
      b20 = LDS8(rb + BB + 4096 + p0);  b21 = LDS8(rb + BB + 4096 + p1);      \
      b30 = LDS8(rb + BB + 6144 + p0);  b31 = LDS8(rb + BB + 6144 + p1);      \
      if (DOSTAGE) { G2L(gBr0, stb + 32768 + L); G2L(gBr1, stb + 40960 + L); }\
      asm volatile("s_waitcnt lgkmcnt(8)" ::: "memory"); SBAR;                \
      BARR; LGK0;                                                             \
      __builtin_amdgcn_s_setprio(1);                                          \
      MMPH(0, 1, x0, x1, y0, y1)                                              \
      __builtin_amdgcn_s_setprio(0); SBAR; BARR;                              \
    }                                                                         \
    { /* phase 2: A mf2,3; stage B2,B3; WB gates ph3/ph4 reads */             \
      bf16x8 x0 = LDS8(rb + RA0 + 4096 + p0), x1 = LDS8(rb + RA0 + 4096 + p1);\
      bf16x8 y0 = LDS8(rb + RA0 + 6144 + p0), y1 = LDS8(rb + RA0 + 6144 + p1);\
      if (DOSTAGE) { G2L(gBr2, stb + 49152 + L); G2L(gBr3, stb + 57344 + L); }\
      SBAR; BARR; LGK0;                                                       \
      __builtin_amdgcn_s_setprio(1);                                          \
      MMPH(2, 3, x0, x1, y0, y1)                                              \
      __builtin_amdgcn_s_setprio(0); SBAR;                                    \
      asm volatile(WBSTR ::: "memory"); SBAR; BARR;                           \
    }                                                                         \
    { /* phase 3: A mf4,5; stage A0,A2 */                                     \
      bf16x8 x0 = LDS8(rb + RA1        + p0), x1 = LDS8(rb + RA1        + p1);\
      bf16x8 y0 = LDS8(rb + RA1 + 2048 + p0), y1 = LDS8(rb + RA1 + 2048 + p1);\
      if (DOSTAGE) { G2L(gAr0, stb + L); G2L(gAr2, stb + 16384 + L); }        \
      SBAR; BARR; LGK0;                                                       \
      __builtin_amdgcn_s_setprio(1);                                          \
      MMPH(4, 5, x0, x1, y0, y1)                                              \
      __builtin_amdgcn_s_setprio(0); SBAR; BARR;                              \
    }                                                                         \
    { /* phase 4: A mf6,7; stage A1,A3; WA gates next tile's ph1/ph2 */       \
      bf16x8 x0 = LDS8(rb + RA1 + 4096 + p0), x1 = LDS8(rb + RA1 + 4096 + p1);\
      bf16x8 y0 = LDS8(rb + RA1 + 6144 + p0), y1 = LDS8(rb + RA1 + 6144 + p1);\
      if (DOSTAGE) { G2L(gAr1, stb + 8192 + L); G2L(gAr3, stb + 24576 + L);   \
                     gAr0 += 128; gAr1 += 128; gAr2 += 128; gAr3 += 128;      \
                     gBr0 += 128; gBr1 += 128; gBr2 += 128; gBr3 += 128; }    \
      SBAR; BARR; LGK0;                                                       \
      __builtin_amdgcn_s_setprio(1);                                          \
      MMPH(6, 7, x0, x1, y0, y1)                                              \
      __builtin_amdgcn_s_setprio(0); SBAR;                                    \
      if (DOWA) { asm volatile("s_waitcnt vmcnt(2)" ::: "memory"); }          \
      SBAR; BARR;                                                             \
    }                                                                         \
  } while (0)

  // ---- prologue: stage tile 0 (FIFO order B0..B3, A0, A2, A1, A3)
  G2L(gBr0, lds + 32768 + L); G2L(gBr1, lds + 40960 + L);
  G2L(gBr2, lds + 49152 + L); G2L(gBr3, lds + 57344 + L);
  G2L(gAr0, lds + L);         G2L(gAr2, lds + 16384 + L);
  G2L(gAr1, lds + 8192 + L);  G2L(gAr3, lds + 24576 + L);
  gAr0 += 128; gAr1 += 128; gAr2 += 128; gAr3 += 128;
  gBr0 += 128; gBr1 += 128; gBr2 += 128; gBr3 += 128;
  asm volatile("s_waitcnt vmcnt(2)" ::: "memory");
  SBAR; BARR;

  char* const bufA = lds;
  char* const bufB = lds + 65536;
  // nt = 12: 5 full double-tiles, then peeled pair (t=10 stages t=11; t=11 none)
  for (int i = 0; i < (nt - 2) / 2; ++i) {
    TILE(bufA, bufB, 1, "s_waitcnt vmcnt(4)", 1);
    TILE(bufB, bufA, 1, "s_waitcnt vmcnt(4)", 1);
  }
  TILE(bufA, bufB, 1, "s_waitcnt vmcnt(4)", 1);
  TILE(bufB, bufA, 0, "s_waitcnt vmcnt(0)", 0);
#undef TILE
#undef MMPH

  // ---- epilogue: 16x16 C layout: col = cl, row = g4*4 + r
  #pragma unroll
  for (int mf = 0; mf < 8; ++mf) {
    #pragma unroll
    for (int nf = 0; nf < 4; ++nf) {
      int n = n0 + wc*64 + nf*16 + cl;
      float bv = bias[n];
      #pragma unroll
      for (int r = 0; r < 4; ++r) {
        long long m = m0 + wr*128 + mf*16 + g4*4 + r;
        float v = acc[mf][nf][r] + bv;
        if (MODE == 0) {
          Cb[m * (long long)N + n] = f2bf(v);
        } else {
          long long gm = c0 + m;
          long long om = (gm & ~(long long)(SEQ-1)) | ((gm - SHIFT_T) & (long long)(SEQ-1));
          Cf[om * (long long)N + n] = v;
        }
      }
    }
  }
}

// ---- per-(window,head) attention: S = QK^T*scale + rel_bias, softmax, O = P V
__global__ __launch_bounds__(256, 4)
void k_attn(const unsigned short* __restrict__ qkv, const float* __restrict__ rel_bias,
            unsigned short* __restrict__ y) {
  int w = blockIdx.x / NHEAD;
  int h = blockIdx.x - w*NHEAD;
  __shared__ unsigned short sQ[64*72], sK[64*72], sV[64*72];
  __shared__ unsigned short sP[4][16*72];
  __shared__ float rb[128];
  int tid = threadIdx.x, lane = tid & 63, wid = tid >> 6;
  int cl = lane & 15, g4 = lane >> 4;

  if (tid < 2*WINSZ - 1) rb[tid] = rel_bias[h*(2*WINSZ-1) + tid];

  const unsigned short* base = qkv + (long long)w*WINSZ*QKV_N + h*HDIM;
  #pragma unroll
  for (int pass = 0; pass < 2; ++pass) {
    int row = (tid >> 3) + pass*32;
    int ch  = tid & 7;
    const unsigned short* src = base + (long long)row*QKV_N + ch*8;
    *(bf16x8*)(sQ + row*72 + ch*8) = *(const bf16x8*)(src);
    *(bf16x8*)(sK + row*72 + ch*8) = *(const bf16x8*)(src + DMODEL);
    *(bf16x8*)(sV + row*72 + ch*8) = *(const bf16x8*)(src + 2*DMODEL);
  }
  __syncthreads();

  f32x4 sc[4];
  #pragma unroll
  for (int nt = 0; nt < 4; ++nt) sc[nt] = (f32x4){0.f,0.f,0.f,0.f};
  #pragma unroll
  for (int kk = 0; kk < 2; ++kk) {
    bf16x8 aq = *(const bf16x8*)(sQ + (wid*16 + cl)*72 + kk*32 + g4*8);
    #pragma unroll
    for (int nt = 0; nt < 4; ++nt) {
      bf16x8 bk = *(const bf16x8*)(sK + (nt*16 + cl)*72 + kk*32 + g4*8);
      sc[nt] = __builtin_amdgcn_mfma_f32_16x16x32_bf16(aq, bk, sc[nt], 0, 0, 0);
    }
  }

  float pv[4][4];
  #pragma unroll
  for (int r = 0; r < 4; ++r) {
    int qi = wid*16 + g4*4 + r;
    float mx = -1e30f;
    #pragma unroll
    for (int nt = 0; nt < 4; ++nt) {
      int kj = nt*16 + cl;
      float v = sc[nt][r]*0.125f + rb[kj - qi + (WINSZ-1)];
      pv[nt][r] = v;
      mx = fmaxf(mx, v);
    }
    #pragma unroll
    for (int m = 1; m < 16; m <<= 1) mx = fmaxf(mx, __shfl_xor(mx, m, 64));
    float sum = 0.f;
    #pragma unroll
    for (int nt = 0; nt < 4; ++nt) { float e = __expf(pv[nt][r]-mx); pv[nt][r] = e; sum += e; }
    #pragma unroll
    for (int m = 1; m < 16; m <<= 1) sum += __shfl_xor(sum, m, 64);
    float inv = 1.f / sum;
    #pragma unroll
    for (int nt = 0; nt < 4; ++nt)
      sP[wid][(g4*4+r)*72 + nt*16 + cl] = f2bf(pv[nt][r]*inv);
  }

  f32x4 o[4];
  #pragma unroll
  for (int nt = 0; nt < 4; ++nt) o[nt] = (f32x4){0.f,0.f,0.f,0.f};
  #pragma unroll
  for (int kk = 0; kk < 2; ++kk) {
    bf16x8 ap = *(const bf16x8*)(&sP[wid][cl*72 + kk*32 + g4*8]);
    #pragma unroll
    for (int nt = 0; nt < 4; ++nt) {
      bf16x8 bv;
      #pragma unroll
      for (int j = 0; j < 8; ++j)
        bv[j] = (short)sV[(kk*32 + g4*8 + j)*72 + nt*16 + cl];
      o[nt] = __builtin_amdgcn_mfma_f32_16x16x32_bf16(ap, bv, o[nt], 0, 0, 0);
    }
  }

  long long tokbase = (long long)w * WINSZ;
  #pragma unroll
  for (int nt = 0; nt < 4; ++nt)
    #pragma unroll
    for (int r = 0; r < 4; ++r) {
      int row = wid*16 + g4*4 + r;
      y[(tokbase + row) * (long long)DMODEL + h*HDIM + nt*16 + cl] = f2bf(o[nt][r]);
    }
}

extern "C" void kernel_launch(void* const* d_in, const int* in_sizes, int n_in,
                              void* d_out, int out_size, void* d_ws, size_t ws_size,
                              hipStream_t stream) {
  const float* x      = (const float*)d_in[0];
  const float* qkv_w  = (const float*)d_in[1];
  const float* qkv_b  = (const float*)d_in[2];
  const float* proj_w = (const float*)d_in[3];
  const float* proj_b = (const float*)d_in[4];
  const float* rel_b  = (const float*)d_in[5];
  float* out = (float*)d_out;

  const long long NTOK = (long long)NBATCH * SEQ;    // 65536
  const size_t wbytes = (size_t)QKV_N*DMODEL*2 + (size_t)DMODEL*DMODEL*2;

  int C = 16;
  for (int c : {1, 2, 4, 8, 16}) {
    size_t tpc = (size_t)NTOK / c;
    size_t need = tpc*QKV_N*2 + tpc*DMODEL*2 + wbytes;
    if (need <= ws_size) { C = c; break; }
  }
  long long tpc = NTOK / C;

  char* ws = (char*)d_ws;
  unsigned short* qkvb = (unsigned short*)ws;
  unsigned short* xb   = (unsigned short*)(ws + (size_t)tpc*QKV_N*2);
  unsigned short* wq   = (unsigned short*)(ws + (size_t)tpc*QKV_N*2 + (size_t)tpc*DMODEL*2);
  unsigned short* wp   = wq + (size_t)QKV_N*DMODEL;

  k_cvt_w<<<(QKV_N*DMODEL/8 + 255)/256, 256, 0, stream>>>(qkv_w, wq, QKV_N*DMODEL/8);
  k_cvt_w<<<(DMODEL*DMODEL/8 + 255)/256, 256, 0, stream>>>(proj_w, wp, DMODEL*DMODEL/8);

  for (int c = 0; c < C; ++c) {
    long long c0 = (long long)c * tpc;
    long long n8 = tpc * DMODEL / 8;
    int cvtGrid = (int)((n8 + 255) / 256); if (cvtGrid > 2048) cvtGrid = 2048;
    k_cvt_x<<<cvtGrid, 256, 0, stream>>>(x, xb, c0, n8);

    int mT = (int)(tpc / 256);
    k_gemm256<0><<<mT * (QKV_N/256), 512, 0, stream>>>(xb, wq, qkv_b, qkvb, nullptr,
                                                       (int)tpc, QKV_N, DMODEL, QKV_N/256, c0);
    k_attn<<<(int)(tpc/WINSZ) * NHEAD, 256, 0, stream>>>(qkvb, rel_b, xb /*reuse as y*/);
    k_gemm256<1><<<mT * (DMODEL/256), 512, 0, stream>>>(xb, wp, proj_b, nullptr, out,
                                                        (int)tpc, DMODEL, DMODEL, DMODEL/256, c0);
  }
}